// Round 10
// baseline (400.355 us; speedup 1.0000x reference)
//
#include <hip/hip_runtime.h>

#define NF 128
#define NR 6
#define CAP 64   // slots per atom; counts ~ Poisson(16), max@100K atoms ~40

// ---------------------------------------------------------------------------
// Pass 1: single-pass bucket append (unchanged from R9).
// ---------------------------------------------------------------------------
__global__ __launch_bounds__(256) void append_kernel(
    const int* __restrict__ idx, int* __restrict__ count,
    int* __restrict__ slots, int E)
{
    int stride = gridDim.x * blockDim.x;
    for (int e = blockIdx.x * blockDim.x + threadIdx.x; e < E; e += stride) {
        int a = idx[e];
        int pos = atomicAdd(&count[a], 1);
        if (pos < CAP) slots[(long)a * CAP + pos] = e;
    }
}

// ---------------------------------------------------------------------------
// Pass 2: gather + rbf projection + swish -> af (global). NO LDS: max
// occupancy for the latency-bound random-row m reads. launch_bounds(256,4)
// caps VGPR at 128 -> 16 waves/CU. Block = 4 waves, 16 atoms; each wave 2
// atoms in parallel (32-lane halves) x 2 sequential; half-lane hl owns
// features 4*hl..4*hl+3 (one float4 = full 512B row per half per edge).
// ---------------------------------------------------------------------------
__global__ __launch_bounds__(256, 4) void gather_kernel(
    const float* __restrict__ m, const int* __restrict__ count,
    const int* __restrict__ slots, const float* __restrict__ rbf,
    const float* __restrict__ W_rbf, float* __restrict__ af, int N)
{
    const int t = threadIdx.x;
    const int lane = t & 63;
    const int w = t >> 6;
    const int h  = lane >> 5;   // half-wave: 0/1
    const int hl = lane & 31;   // lane within half

    // per-lane W_rbf rows for features 4*hl..4*hl+3
    float wr[4][NR];
#pragma unroll
    for (int c = 0; c < 4; ++c)
#pragma unroll
        for (int r = 0; r < NR; ++r)
            wr[c][r] = W_rbf[(4 * hl + c) * NR + r];

    const int nb = blockIdx.x * 16 + w * 4;

    for (int ta = 0; ta < 2; ++ta) {
        const int n = nb + ta * 2 + h;
        float a0 = 0.f, a1 = 0.f, a2 = 0.f, a3 = 0.f;
        int cnt = 0;
        long base = 0;
        if (n < N) {
            cnt = min(count[n], CAP);
            base = (long)n * CAP;
        }

        // 32-deep register cache of this half's slot entries
        int eid = (hl < cnt) ? slots[base + hl] : 0;

        for (int p0 = 0; p0 < cnt; p0 += 4) {
            int bc = cnt - p0; if (bc > 4) bc = 4;
            int e4[4];
            float4 mv[4];
            float2 rv[4][3];
#pragma unroll
            for (int k = 0; k < 4; ++k) {
                int off = p0 + k;
                int e;
                if (off < 32) e = __shfl(eid, (h << 5) + off);
                else e = (off < cnt) ? slots[base + off] : __shfl(eid, h << 5);
                if (k >= bc) e = __shfl(eid, h << 5);  // clamp to safe row
                e4[k] = e;
            }
#pragma unroll
            for (int k = 0; k < 4; ++k) {
                mv[k] = *(const float4*)(m + (long)e4[k] * NF + hl * 4);
                const float2* rp = (const float2*)(rbf + (long)e4[k] * NR);
                rv[k][0] = rp[0]; rv[k][1] = rp[1]; rv[k][2] = rp[2];
            }
#pragma unroll
            for (int k = 0; k < 4; ++k) {
                if (k < bc) {
                    float f0 = rv[k][0].x * wr[0][0];
                    float f1 = rv[k][0].x * wr[1][0];
                    float f2 = rv[k][0].x * wr[2][0];
                    float f3 = rv[k][0].x * wr[3][0];
                    f0 = fmaf(rv[k][0].y, wr[0][1], f0);
                    f1 = fmaf(rv[k][0].y, wr[1][1], f1);
                    f2 = fmaf(rv[k][0].y, wr[2][1], f2);
                    f3 = fmaf(rv[k][0].y, wr[3][1], f3);
                    f0 = fmaf(rv[k][1].x, wr[0][2], f0);
                    f1 = fmaf(rv[k][1].x, wr[1][2], f1);
                    f2 = fmaf(rv[k][1].x, wr[2][2], f2);
                    f3 = fmaf(rv[k][1].x, wr[3][2], f3);
                    f0 = fmaf(rv[k][1].y, wr[0][3], f0);
                    f1 = fmaf(rv[k][1].y, wr[1][3], f1);
                    f2 = fmaf(rv[k][1].y, wr[2][3], f2);
                    f3 = fmaf(rv[k][1].y, wr[3][3], f3);
                    f0 = fmaf(rv[k][2].x, wr[0][4], f0);
                    f1 = fmaf(rv[k][2].x, wr[1][4], f1);
                    f2 = fmaf(rv[k][2].x, wr[2][4], f2);
                    f3 = fmaf(rv[k][2].x, wr[3][4], f3);
                    f0 = fmaf(rv[k][2].y, wr[0][5], f0);
                    f1 = fmaf(rv[k][2].y, wr[1][5], f1);
                    f2 = fmaf(rv[k][2].y, wr[2][5], f2);
                    f3 = fmaf(rv[k][2].y, wr[3][5], f3);
                    a0 = fmaf(mv[k].x, f0, a0);
                    a1 = fmaf(mv[k].y, f1, a1);
                    a2 = fmaf(mv[k].z, f2, a2);
                    a3 = fmaf(mv[k].w, f3, a3);
                }
            }
        }

        if (n < N) {
            float s0 = a0 / (1.f + __expf(-a0));
            float s1 = a1 / (1.f + __expf(-a1));
            float s2 = a2 / (1.f + __expf(-a2));
            float s3 = a3 / (1.f + __expf(-a3));
            *(float4*)(af + (long)n * NF + 4 * hl) = make_float4(s0, s1, s2, s3);
        }
    }
}

// ---------------------------------------------------------------------------
// Pass 3: per-atom MLP. Block = 256 = 4 waves, 64 atoms/block (16 per wave).
// W1t reads are wave-uniform (broadcast) -> amortized over 16 atoms/wave.
// ---------------------------------------------------------------------------
__global__ __launch_bounds__(256, 2) void mlp_kernel(
    const float* __restrict__ af, const float* __restrict__ W1,
    const float* __restrict__ b1, const float* __restrict__ W2,
    const float* __restrict__ b2, float* __restrict__ out, int N)
{
    __shared__ float W1t[128][68];   // 34.8 KB transposed W1
    __shared__ float sb[64][132];    // 33.8 KB swish-ed atom features

    const int t = threadIdx.x;

    // stage W1 transposed
    for (int k4 = t; k4 < 2048; k4 += 256) {
        int k = k4 * 4;
        int j = k >> 7, f = k & 127;
        float4 v = *(const float4*)(W1 + k);
        W1t[f + 0][j] = v.x; W1t[f + 1][j] = v.y;
        W1t[f + 2][j] = v.z; W1t[f + 3][j] = v.w;
    }

    // stage 64 atom rows (already swish-ed by gather), coalesced
    const int nb = blockIdx.x * 64;
    for (int k4 = t; k4 < 2048; k4 += 256) {
        int row = k4 >> 5, col = (k4 & 31) * 4;
        int n = nb + row;
        float4 v = make_float4(0.f, 0.f, 0.f, 0.f);
        if (n < N) v = *(const float4*)(af + (long)n * NF + col);
        *(float4*)&sb[row][col] = v;
    }
    __syncthreads();

    const int lane = t & 63, w = t >> 6;
    const int ag = lane >> 4, lj = lane & 15;
    const int abase = w * 16 + ag * 4;

    float4 bv = *(const float4*)(b1 + 4 * lj);
    float h[4][4];
#pragma unroll
    for (int i = 0; i < 4; ++i) {
        h[i][0] = bv.x; h[i][1] = bv.y; h[i][2] = bv.z; h[i][3] = bv.w;
    }

    for (int f = 0; f < 128; f += 4) {
        float4 w0  = *(const float4*)&W1t[f + 0][4 * lj];
        float4 w1v = *(const float4*)&W1t[f + 1][4 * lj];
        float4 w2v = *(const float4*)&W1t[f + 2][4 * lj];
        float4 w3v = *(const float4*)&W1t[f + 3][4 * lj];
#pragma unroll
        for (int i = 0; i < 4; ++i) {
            float4 sv = *(const float4*)&sb[abase + i][f];
            h[i][0] = fmaf(sv.w, w3v.x, fmaf(sv.z, w2v.x, fmaf(sv.y, w1v.x, fmaf(sv.x, w0.x, h[i][0]))));
            h[i][1] = fmaf(sv.w, w3v.y, fmaf(sv.z, w2v.y, fmaf(sv.y, w1v.y, fmaf(sv.x, w0.y, h[i][1]))));
            h[i][2] = fmaf(sv.w, w3v.z, fmaf(sv.z, w2v.z, fmaf(sv.y, w1v.z, fmaf(sv.x, w0.z, h[i][2]))));
            h[i][3] = fmaf(sv.w, w3v.w, fmaf(sv.z, w2v.w, fmaf(sv.y, w1v.w, fmaf(sv.x, w0.w, h[i][3]))));
        }
    }

    float4 w2v4 = *(const float4*)(W2 + 4 * lj);
    float b2v = b2[0];

    float c[4];
#pragma unroll
    for (int i = 0; i < 4; ++i) {
        float v;
        v  = (h[i][0] / (1.f + __expf(-h[i][0]))) * w2v4.x;
        v += (h[i][1] / (1.f + __expf(-h[i][1]))) * w2v4.y;
        v += (h[i][2] / (1.f + __expf(-h[i][2]))) * w2v4.z;
        v += (h[i][3] / (1.f + __expf(-h[i][3]))) * w2v4.w;
        c[i] = v;
    }
#pragma unroll
    for (int d = 1; d < 16; d <<= 1) {
        c[0] += __shfl_xor(c[0], d);
        c[1] += __shfl_xor(c[1], d);
        c[2] += __shfl_xor(c[2], d);
        c[3] += __shfl_xor(c[3], d);
    }

    if (lj < 4) {
        int n = nb + abase + lj;
        if (n < N) out[n] = c[lj] + b2v;
    }
}

extern "C" void kernel_launch(void* const* d_in, const int* in_sizes, int n_in,
                              void* d_out, int out_size, void* d_ws, size_t ws_size,
                              hipStream_t stream) {
    const float* m     = (const float*)d_in[0];
    const float* rbf   = (const float*)d_in[1];
    const int*   idx   = (const int*)d_in[2];
    const float* W_rbf = (const float*)d_in[4];
    const float* W1    = (const float*)d_in[5];
    const float* b1    = (const float*)d_in[6];
    const float* W2    = (const float*)d_in[7];
    const float* b2    = (const float*)d_in[8];
    float* out = (float*)d_out;

    const int E = in_sizes[2];   // one atom index per edge
    const int N = out_size;      // out is [N, 1]

    int* count = (int*)d_ws;                      // N ints
    int* slots = count + ((N + 63) & ~63);        // N*CAP ints (25.6 MB)
    float* af  = (float*)(slots + (long)((N + 63) & ~63) * CAP);  // N*128 f32

    hipMemsetAsync(count, 0, (size_t)N * sizeof(int), stream);
    append_kernel<<<2048, 256, 0, stream>>>(idx, count, slots, E);
    gather_kernel<<<(N + 15) / 16, 256, 0, stream>>>(
        m, count, slots, rbf, W_rbf, af, N);
    mlp_kernel<<<(N + 63) / 64, 256, 0, stream>>>(af, W1, b1, W2, b2, out, N);
}

// Round 11
// 379.725 us; speedup vs baseline: 1.0543x; 1.0543x over previous
//
#include <hip/hip_runtime.h>

#define NF 128
#define NR 6
#define CAP 64   // slots per atom; counts ~ Poisson(16), max@100K atoms ~40

// ---------------------------------------------------------------------------
// Pass 1: single-pass bucket append. One int4 of edges per thread (exact
// grid): 4 INDEPENDENT atomic->store chains per thread for latency hiding,
// nontemporal slot stores (no RMW allocate on the scattered 4B writes).
// ---------------------------------------------------------------------------
__global__ __launch_bounds__(256) void append_kernel(
    const int* __restrict__ idx, int* __restrict__ count,
    int* __restrict__ slots, int E)
{
    const int t = blockIdx.x * blockDim.x + threadIdx.x;
    const int e0 = t * 4;
    if (e0 + 3 < E) {
        int4 v = *(const int4*)(idx + e0);
        int p0 = atomicAdd(&count[v.x], 1);
        int p1 = atomicAdd(&count[v.y], 1);
        int p2 = atomicAdd(&count[v.z], 1);
        int p3 = atomicAdd(&count[v.w], 1);
        if (p0 < CAP) __builtin_nontemporal_store(e0 + 0, &slots[(long)v.x * CAP + p0]);
        if (p1 < CAP) __builtin_nontemporal_store(e0 + 1, &slots[(long)v.y * CAP + p1]);
        if (p2 < CAP) __builtin_nontemporal_store(e0 + 2, &slots[(long)v.z * CAP + p2]);
        if (p3 < CAP) __builtin_nontemporal_store(e0 + 3, &slots[(long)v.w * CAP + p3]);
    } else {
        for (int e = e0; e < E; ++e) {
            int a = idx[e];
            int pos = atomicAdd(&count[a], 1);
            if (pos < CAP) slots[(long)a * CAP + pos] = e;
        }
    }
}

// ---------------------------------------------------------------------------
// Pass 2: fused gather + rbf projection + per-atom MLP (byte-identical to R9).
// ---------------------------------------------------------------------------
__global__ __launch_bounds__(256) void gather_mlp_kernel(
    const float* __restrict__ m, const int* __restrict__ count,
    const int* __restrict__ slots, const float* __restrict__ rbf,
    const float* __restrict__ W_rbf, const float* __restrict__ W1,
    const float* __restrict__ b1, const float* __restrict__ W2,
    const float* __restrict__ b2, float* __restrict__ out, int N)
{
    __shared__ float W1t[128][68];   // transposed W1, padded
    __shared__ float sb[4][4][132];  // [wave][atom][feat], padded

    const int t = threadIdx.x;
    const int lane = t & 63;
    const int w = t >> 6;
    const int h  = lane >> 5;   // half-wave: 0/1
    const int hl = lane & 31;   // lane within half

    // stage W1 transposed (vectorized): W1 is [64][128] row-major
    for (int k4 = t; k4 < 64 * 128 / 4; k4 += 256) {
        int k = k4 * 4;
        int j = k >> 7, f = k & 127;
        float4 v = *(const float4*)(W1 + k);
        W1t[f + 0][j] = v.x; W1t[f + 1][j] = v.y;
        W1t[f + 2][j] = v.z; W1t[f + 3][j] = v.w;
    }

    // per-lane W_rbf rows for features 4*hl..4*hl+3
    float wr[4][NR];
#pragma unroll
    for (int c = 0; c < 4; ++c)
#pragma unroll
        for (int r = 0; r < NR; ++r)
            wr[c][r] = W_rbf[(4 * hl + c) * NR + r];

    __syncthreads();

    const int nb = blockIdx.x * 16 + w * 4;

    for (int ta = 0; ta < 2; ++ta) {
        const int n = nb + ta * 2 + h;
        float a0 = 0.f, a1 = 0.f, a2 = 0.f, a3 = 0.f;
        int cnt = 0;
        long base = 0;
        if (n < N) {
            cnt = min(count[n], CAP);
            base = (long)n * CAP;
        }

        // 32-deep register cache of this half's slot entries
        int eid = (hl < cnt) ? slots[base + hl] : 0;

        for (int p0 = 0; p0 < cnt; p0 += 4) {
            int bc = cnt - p0; if (bc > 4) bc = 4;
            int e4[4];
            float4 mv[4];
            float2 rv[4][3];
#pragma unroll
            for (int k = 0; k < 4; ++k) {
                int off = p0 + k;
                int e;
                if (off < 32) e = __shfl(eid, (h << 5) + off);
                else e = (off < cnt) ? slots[base + off] : __shfl(eid, h << 5);
                if (k >= bc) e = __shfl(eid, h << 5);  // clamp to safe row
                e4[k] = e;
            }
#pragma unroll
            for (int k = 0; k < 4; ++k) {
                mv[k] = *(const float4*)(m + (long)e4[k] * NF + hl * 4);
                const float2* rp = (const float2*)(rbf + (long)e4[k] * NR);
                rv[k][0] = rp[0]; rv[k][1] = rp[1]; rv[k][2] = rp[2];
            }
#pragma unroll
            for (int k = 0; k < 4; ++k) {
                if (k < bc) {
                    float f0 = rv[k][0].x * wr[0][0];
                    float f1 = rv[k][0].x * wr[1][0];
                    float f2 = rv[k][0].x * wr[2][0];
                    float f3 = rv[k][0].x * wr[3][0];
                    f0 = fmaf(rv[k][0].y, wr[0][1], f0);
                    f1 = fmaf(rv[k][0].y, wr[1][1], f1);
                    f2 = fmaf(rv[k][0].y, wr[2][1], f2);
                    f3 = fmaf(rv[k][0].y, wr[3][1], f3);
                    f0 = fmaf(rv[k][1].x, wr[0][2], f0);
                    f1 = fmaf(rv[k][1].x, wr[1][2], f1);
                    f2 = fmaf(rv[k][1].x, wr[2][2], f2);
                    f3 = fmaf(rv[k][1].x, wr[3][2], f3);
                    f0 = fmaf(rv[k][1].y, wr[0][3], f0);
                    f1 = fmaf(rv[k][1].y, wr[1][3], f1);
                    f2 = fmaf(rv[k][1].y, wr[2][3], f2);
                    f3 = fmaf(rv[k][1].y, wr[3][3], f3);
                    f0 = fmaf(rv[k][2].x, wr[0][4], f0);
                    f1 = fmaf(rv[k][2].x, wr[1][4], f1);
                    f2 = fmaf(rv[k][2].x, wr[2][4], f2);
                    f3 = fmaf(rv[k][2].x, wr[3][4], f3);
                    f0 = fmaf(rv[k][2].y, wr[0][5], f0);
                    f1 = fmaf(rv[k][2].y, wr[1][5], f1);
                    f2 = fmaf(rv[k][2].y, wr[2][5], f2);
                    f3 = fmaf(rv[k][2].y, wr[3][5], f3);
                    a0 = fmaf(mv[k].x, f0, a0);
                    a1 = fmaf(mv[k].y, f1, a1);
                    a2 = fmaf(mv[k].z, f2, a2);
                    a3 = fmaf(mv[k].w, f3, a3);
                }
            }
        }

        float s0 = a0 / (1.f + __expf(-a0));
        float s1 = a1 / (1.f + __expf(-a1));
        float s2 = a2 / (1.f + __expf(-a2));
        float s3 = a3 / (1.f + __expf(-a3));
        *(float4*)&sb[w][ta * 2 + h][4 * hl] = make_float4(s0, s1, s2, s3);
    }

    // layer 1 (sb[w] wave-private: no block sync needed)
    const int ag = lane >> 4;
    const int lj = lane & 15;

    float4 bv = *(const float4*)(b1 + 4 * lj);
    float h0 = bv.x, h1 = bv.y, h2 = bv.z, h3 = bv.w;

    for (int f = 0; f < 128; f += 4) {
        float4 sv = *(const float4*)&sb[w][ag][f];
        float4 w0 = *(const float4*)&W1t[f + 0][4 * lj];
        float4 w1v = *(const float4*)&W1t[f + 1][4 * lj];
        float4 w2v = *(const float4*)&W1t[f + 2][4 * lj];
        float4 w3v = *(const float4*)&W1t[f + 3][4 * lj];
        h0 = fmaf(sv.x, w0.x, h0);  h1 = fmaf(sv.x, w0.y, h1);
        h2 = fmaf(sv.x, w0.z, h2);  h3 = fmaf(sv.x, w0.w, h3);
        h0 = fmaf(sv.y, w1v.x, h0); h1 = fmaf(sv.y, w1v.y, h1);
        h2 = fmaf(sv.y, w1v.z, h2); h3 = fmaf(sv.y, w1v.w, h3);
        h0 = fmaf(sv.z, w2v.x, h0); h1 = fmaf(sv.z, w2v.y, h1);
        h2 = fmaf(sv.z, w2v.z, h2); h3 = fmaf(sv.z, w2v.w, h3);
        h0 = fmaf(sv.w, w3v.x, h0); h1 = fmaf(sv.w, w3v.y, h1);
        h2 = fmaf(sv.w, w3v.z, h2); h3 = fmaf(sv.w, w3v.w, h3);
    }

    float4 w2 = *(const float4*)(W2 + 4 * lj);
    float r = (h0 / (1.f + __expf(-h0))) * w2.x
            + (h1 / (1.f + __expf(-h1))) * w2.y
            + (h2 / (1.f + __expf(-h2))) * w2.z
            + (h3 / (1.f + __expf(-h3))) * w2.w;

    r += __shfl_xor(r, 1);
    r += __shfl_xor(r, 2);
    r += __shfl_xor(r, 4);
    r += __shfl_xor(r, 8);

    int n = nb + ag;
    if (lj == 0 && n < N) out[n] = r + b2[0];
}

extern "C" void kernel_launch(void* const* d_in, const int* in_sizes, int n_in,
                              void* d_out, int out_size, void* d_ws, size_t ws_size,
                              hipStream_t stream) {
    const float* m     = (const float*)d_in[0];
    const float* rbf   = (const float*)d_in[1];
    const int*   idx   = (const int*)d_in[2];
    const float* W_rbf = (const float*)d_in[4];
    const float* W1    = (const float*)d_in[5];
    const float* b1    = (const float*)d_in[6];
    const float* W2    = (const float*)d_in[7];
    const float* b2    = (const float*)d_in[8];
    float* out = (float*)d_out;

    const int E = in_sizes[2];   // one atom index per edge
    const int N = out_size;      // out is [N, 1]

    int* count = (int*)d_ws;                      // N ints
    int* slots = count + ((N + 63) & ~63);        // N*CAP ints (25.6 MB)

    hipMemsetAsync(count, 0, (size_t)N * sizeof(int), stream);
    append_kernel<<<(E + 1023) / 1024, 256, 0, stream>>>(idx, count, slots, E);
    gather_mlp_kernel<<<(N + 15) / 16, 256, 0, stream>>>(
        m, count, slots, rbf, W_rbf, W1, b1, W2, b2, out, N);
}